// Round 1
// baseline (2777.332 us; speedup 1.0000x reference)
//
#include <hip/hip_runtime.h>
#include <cstdint>
#include <cstddef>

// Problem constants
#define A_LEN  2048
#define D_DIM  512
#define NHEADS 4
#define HDIM   128
#define B_SZ   4
#define ROWS   (B_SZ * A_LEN)   // 8192
#define LN_EPS 1e-5f

// ---------------------------------------------------------------------------
// LayerNorm (optionally preceded by swish). One wave (64 lanes) per row of 512.
// 4 rows per 256-thread block.
// ---------------------------------------------------------------------------
__global__ __launch_bounds__(256) void ln_swish_kernel(
    const float* __restrict__ in, float* __restrict__ out,
    const float* __restrict__ w, const float* __restrict__ bvec, int do_swish)
{
    int row  = blockIdx.x * 4 + (threadIdx.x >> 6);
    int lane = threadIdx.x & 63;
    const float* x = in + (size_t)row * D_DIM + lane * 8;
    float4 a  = *(const float4*)x;
    float4 b4 = *(const float4*)(x + 4);
    float v[8] = {a.x, a.y, a.z, a.w, b4.x, b4.y, b4.z, b4.w};
    if (do_swish) {
#pragma unroll
        for (int j = 0; j < 8; ++j) v[j] = v[j] / (1.f + __expf(-v[j]));
    }
    float s = 0.f, s2 = 0.f;
#pragma unroll
    for (int j = 0; j < 8; ++j) { s += v[j]; s2 += v[j] * v[j]; }
#pragma unroll
    for (int off = 32; off; off >>= 1) {
        s  += __shfl_xor(s,  off);
        s2 += __shfl_xor(s2, off);
    }
    float mean = s * (1.f / D_DIM);
    float var  = s2 * (1.f / D_DIM) - mean * mean;
    float inv  = rsqrtf(var + LN_EPS);
    float* o = out + (size_t)row * D_DIM + lane * 8;
    const float* wp = w + lane * 8;
    const float* bp = bvec + lane * 8;
#pragma unroll
    for (int j = 0; j < 8; ++j)
        o[j] = (v[j] - mean) * inv * wp[j] + bp[j];
}

// ---------------------------------------------------------------------------
// GEMM: C[M,N] = A[M,K] * W[N,K]^T (+ bias[N]).  Both row-major, K contiguous.
// 64x64 block tile, BK=32, 256 threads, 4x4 register micro-tile.
// ---------------------------------------------------------------------------
#define BM 64
#define BN 64
#define BK 32

__global__ __launch_bounds__(256) void gemm_abt(
    const float* __restrict__ Am, const float* __restrict__ Wm,
    const float* __restrict__ bias, float* __restrict__ C,
    int M, int N, int K)
{
    __shared__ float As[BK][BM + 4];   // padded: row stride 68 floats (16B-aligned)
    __shared__ float Bs[BK][BN + 4];
    int tid = threadIdx.x;
    int m0 = blockIdx.x * BM;
    int n0 = blockIdx.y * BN;
    int tx = tid & 15, ty = tid >> 4;
    float acc[4][4] = {};

    for (int k0 = 0; k0 < K; k0 += BK) {
#pragma unroll
        for (int l = 0; l < 2; ++l) {
            int idx = tid + l * 256;      // float4 index 0..511
            int row = idx >> 3;           // 0..63
            int kc  = (idx & 7) << 2;     // 0,4,...,28
            float4 a4 = *(const float4*)(Am + (size_t)(m0 + row) * K + k0 + kc);
            As[kc + 0][row] = a4.x; As[kc + 1][row] = a4.y;
            As[kc + 2][row] = a4.z; As[kc + 3][row] = a4.w;
            float4 w4 = *(const float4*)(Wm + (size_t)(n0 + row) * K + k0 + kc);
            Bs[kc + 0][row] = w4.x; Bs[kc + 1][row] = w4.y;
            Bs[kc + 2][row] = w4.z; Bs[kc + 3][row] = w4.w;
        }
        __syncthreads();
#pragma unroll
        for (int kk = 0; kk < BK; ++kk) {
            float ar[4], br[4];
            *(float4*)ar = *(const float4*)&As[kk][ty * 4];
            *(float4*)br = *(const float4*)&Bs[kk][tx * 4];
#pragma unroll
            for (int i = 0; i < 4; ++i)
#pragma unroll
                for (int j = 0; j < 4; ++j)
                    acc[i][j] = fmaf(ar[i], br[j], acc[i][j]);
        }
        __syncthreads();
    }

    float bv[4] = {0.f, 0.f, 0.f, 0.f};
    if (bias) {
#pragma unroll
        for (int j = 0; j < 4; ++j) bv[j] = bias[n0 + tx * 4 + j];
    }
#pragma unroll
    for (int i = 0; i < 4; ++i) {
        float4 o;
        o.x = acc[i][0] + bv[0]; o.y = acc[i][1] + bv[1];
        o.z = acc[i][2] + bv[2]; o.w = acc[i][3] + bv[3];
        *(float4*)(C + (size_t)(m0 + ty * 4 + i) * N + n0 + tx * 4) = o;
    }
}

// ---------------------------------------------------------------------------
// Masked attention for one (b, h, 8-q-row tile).
// scores (8 x 2048) materialized in LDS; wave-parallel softmax; PV with
// coalesced V reads.  Q/K/V layout: (B*A, 512) with head offset h*128.
// connectivity: int32 (B,1,A,A), nonzero = keep.
// ---------------------------------------------------------------------------
#define TQ 8

__global__ __launch_bounds__(256) void attn_kernel(
    const float* __restrict__ Q, const float* __restrict__ K,
    const float* __restrict__ V, const int* __restrict__ conn,
    float* __restrict__ O)
{
    int bh = blockIdx.y;            // 0..15
    int b  = bh >> 2, h = bh & 3;
    int q0 = blockIdx.x * TQ;
    int tid = threadIdx.x;

    __shared__ float q_s[TQ][HDIM];       // 4 KB
    __shared__ float s_s[TQ][A_LEN];      // 64 KB
    __shared__ float rsum[TQ];

    const size_t base = ((size_t)b * A_LEN) * D_DIM + h * HDIM;

    // load Q tile: 8 rows x 128
    {
        int q = tid >> 5, d4 = (tid & 31) << 2;
        *(float4*)&q_s[q][d4] =
            *(const float4*)(Q + base + (size_t)(q0 + q) * D_DIM + d4);
    }
    __syncthreads();

    // scores
    const float scale = 0.08838834764831845f;   // 1/sqrt(128)
    const int* connb = conn + (size_t)b * A_LEN * A_LEN;
    for (int k = tid; k < A_LEN; k += 256) {
        const float* krow = K + base + (size_t)k * D_DIM;
        float acc[TQ] = {};
#pragma unroll 8
        for (int kk = 0; kk < HDIM; kk += 4) {
            float4 kf = *(const float4*)(krow + kk);
#pragma unroll
            for (int q = 0; q < TQ; ++q) {
                float4 qf = *(const float4*)&q_s[q][kk];
                acc[q] += qf.x * kf.x + qf.y * kf.y + qf.z * kf.z + qf.w * kf.w;
            }
        }
#pragma unroll
        for (int q = 0; q < TQ; ++q) {
            int c = connb[(size_t)(q0 + q) * A_LEN + k];
            s_s[q][k] = c ? acc[q] * scale : -1e30f;
        }
    }
    __syncthreads();

    // softmax: wave w handles rows w and w+4
    int wave = tid >> 6, lane = tid & 63;
    for (int q = wave; q < TQ; q += 4) {
        float m = -1e30f;
        for (int k = lane; k < A_LEN; k += 64) m = fmaxf(m, s_s[q][k]);
#pragma unroll
        for (int off = 32; off; off >>= 1) m = fmaxf(m, __shfl_xor(m, off));
        float sum = 0.f;
        for (int k = lane; k < A_LEN; k += 64) {
            float p = __expf(s_s[q][k] - m);
            s_s[q][k] = p;
            sum += p;
        }
#pragma unroll
        for (int off = 32; off; off >>= 1) sum += __shfl_xor(sum, off);
        if (lane == 0) rsum[q] = 1.f / sum;
    }
    __syncthreads();

    // PV: tid = half*128 + d ; half handles q = half*4 .. +3
    int half = tid >> 7, d = tid & 127;
    float acc[4] = {};
    const float* vbase = V + base + d;
    for (int k = 0; k < A_LEN; ++k) {
        float vf = vbase[(size_t)k * D_DIM];
#pragma unroll
        for (int q = 0; q < 4; ++q)
            acc[q] += s_s[half * 4 + q][k] * vf;
    }
#pragma unroll
    for (int q = 0; q < 4; ++q) {
        int qq = half * 4 + q;
        O[((size_t)b * A_LEN + q0 + qq) * D_DIM + h * HDIM + d] =
            acc[q] * rsum[qq];
    }
}

// ---------------------------------------------------------------------------
extern "C" void kernel_launch(void* const* d_in, const int* in_sizes, int n_in,
                              void* d_out, int out_size, void* d_ws, size_t ws_size,
                              hipStream_t stream)
{
    const float* x      = (const float*)d_in[0];
    const int*   conn   = (const int*)d_in[1];   // bool -> int32 (harness convention)
    const float* Wq     = (const float*)d_in[2];
    const float* Wk     = (const float*)d_in[3];
    const float* Wv     = (const float*)d_in[4];
    const float* norm_w = (const float*)d_in[5];
    const float* norm_b = (const float*)d_in[6];
    const float* ln1_w  = (const float*)d_in[7];
    const float* ln1_b  = (const float*)d_in[8];
    const float* fc1_w  = (const float*)d_in[9];
    const float* fc1_b  = (const float*)d_in[10];
    const float* ln2_w  = (const float*)d_in[11];
    const float* ln2_b  = (const float*)d_in[12];
    const float* fc2_w  = (const float*)d_in[13];
    const float* fc2_b  = (const float*)d_in[14];
    float* out = (float*)d_out;

    const size_t NELEM = (size_t)ROWS * D_DIM;   // 4,194,304
    float* xn = (float*)d_ws;          // 16 MB
    float* Qb = xn + NELEM;            // 16 MB
    float* Kb = Qb + NELEM;            // 16 MB
    float* Vb = Kb + NELEM;            // 16 MB  (total 64 MB)

    dim3 lnGrid(ROWS / 4), lnBlk(256);
    dim3 gemmGrid(ROWS / BM, D_DIM / BN), gemmBlk(256);
    dim3 attnGrid(A_LEN / TQ, B_SZ * NHEADS), attnBlk(256);

    // xn = LN(x)
    ln_swish_kernel<<<lnGrid, lnBlk, 0, stream>>>(x, xn, norm_w, norm_b, 0);
    // Q/K/V = xn @ W^T
    gemm_abt<<<gemmGrid, gemmBlk, 0, stream>>>(xn, Wq, nullptr, Qb, ROWS, D_DIM, D_DIM);
    gemm_abt<<<gemmGrid, gemmBlk, 0, stream>>>(xn, Wk, nullptr, Kb, ROWS, D_DIM, D_DIM);
    gemm_abt<<<gemmGrid, gemmBlk, 0, stream>>>(xn, Wv, nullptr, Vb, ROWS, D_DIM, D_DIM);
    // attention -> reuse xn
    attn_kernel<<<attnGrid, attnBlk, 0, stream>>>(Qb, Kb, Vb, conn, xn);
    // y1 = LN(swish(attn_out)) -> Qb
    ln_swish_kernel<<<lnGrid, lnBlk, 0, stream>>>(xn, Qb, ln1_w, ln1_b, 1);
    // h1 = y1 @ fc1^T + b1 -> Kb
    gemm_abt<<<gemmGrid, gemmBlk, 0, stream>>>(Qb, fc1_w, fc1_b, Kb, ROWS, D_DIM, D_DIM);
    // y2 = LN(swish(h1)) -> Vb
    ln_swish_kernel<<<lnGrid, lnBlk, 0, stream>>>(Kb, Vb, ln2_w, ln2_b, 1);
    // h2 = y2 @ fc2^T + b2 -> Qb
    gemm_abt<<<gemmGrid, gemmBlk, 0, stream>>>(Vb, fc2_w, fc2_b, Qb, ROWS, D_DIM, D_DIM);
    // out = LN(h2)
    ln_swish_kernel<<<lnGrid, lnBlk, 0, stream>>>(Qb, out, norm_w, norm_b, 0);
}

// Round 2
// 497.746 us; speedup vs baseline: 5.5798x; 5.5798x over previous
//
#include <hip/hip_runtime.h>
#include <cstdint>
#include <cstddef>

#define A_LEN  2048
#define D_DIM  512
#define NHEADS 4
#define HDIM   128
#define B_SZ   4
#define ROWS   (B_SZ * A_LEN)   // 8192
#define LN_EPS 1e-5f

typedef __bf16 bf16x8 __attribute__((ext_vector_type(8)));
typedef __bf16 bf16x4 __attribute__((ext_vector_type(4)));
typedef float  f32x4  __attribute__((ext_vector_type(4)));

// ---------------------------------------------------------------------------
// LayerNorm (optional swish before), f32 in, bf16 or f32 out. 1 wave / row.
// ---------------------------------------------------------------------------
__global__ __launch_bounds__(256) void ln_kernel(
    const float* __restrict__ in, void* __restrict__ out,
    const float* __restrict__ w, const float* __restrict__ bvec,
    int do_swish, int out_bf16)
{
    int row  = blockIdx.x * 4 + (threadIdx.x >> 6);
    int lane = threadIdx.x & 63;
    const float* x = in + (size_t)row * D_DIM + lane * 8;
    float4 a  = *(const float4*)x;
    float4 b4 = *(const float4*)(x + 4);
    float v[8] = {a.x, a.y, a.z, a.w, b4.x, b4.y, b4.z, b4.w};
    if (do_swish) {
#pragma unroll
        for (int j = 0; j < 8; ++j) v[j] = v[j] / (1.f + __expf(-v[j]));
    }
    float s = 0.f, s2 = 0.f;
#pragma unroll
    for (int j = 0; j < 8; ++j) { s += v[j]; s2 += v[j] * v[j]; }
#pragma unroll
    for (int off = 32; off; off >>= 1) {
        s  += __shfl_xor(s,  off);
        s2 += __shfl_xor(s2, off);
    }
    float mean = s * (1.f / D_DIM);
    float var  = s2 * (1.f / D_DIM) - mean * mean;
    float inv  = rsqrtf(var + LN_EPS);
    const float* wp = w + lane * 8;
    const float* bp = bvec + lane * 8;
    float r[8];
#pragma unroll
    for (int j = 0; j < 8; ++j) r[j] = (v[j] - mean) * inv * wp[j] + bp[j];
    if (out_bf16) {
        bf16x8 ov;
#pragma unroll
        for (int j = 0; j < 8; ++j) ov[j] = (__bf16)r[j];
        *(bf16x8*)((__bf16*)out + (size_t)row * D_DIM + lane * 8) = ov;
    } else {
        float* o = (float*)out + (size_t)row * D_DIM + lane * 8;
        float4 o0 = {r[0], r[1], r[2], r[3]}, o1 = {r[4], r[5], r[6], r[7]};
        *(float4*)o = o0; *(float4*)(o + 4) = o1;
    }
}

// ---------------------------------------------------------------------------
// f32 -> bf16 copy (weights): n elements, 8 per thread
// ---------------------------------------------------------------------------
__global__ __launch_bounds__(256) void conv_w_kernel(
    const float* __restrict__ src, __bf16* __restrict__ dst)
{
    size_t i = ((size_t)blockIdx.x * 256 + threadIdx.x) * 8;
    float4 a = *(const float4*)(src + i);
    float4 b = *(const float4*)(src + i + 4);
    bf16x8 o;
    o[0]=(__bf16)a.x; o[1]=(__bf16)a.y; o[2]=(__bf16)a.z; o[3]=(__bf16)a.w;
    o[4]=(__bf16)b.x; o[5]=(__bf16)b.y; o[6]=(__bf16)b.z; o[7]=(__bf16)b.w;
    *(bf16x8*)(dst + i) = o;
}

// ---------------------------------------------------------------------------
// connectivity int32 (B,1,A,A) -> bitmask uint32 [B][A][A/32]
// ---------------------------------------------------------------------------
__global__ __launch_bounds__(256) void mask_pack_kernel(
    const int* __restrict__ conn, uint32_t* __restrict__ mp)
{
    size_t i = (size_t)blockIdx.x * 256 + threadIdx.x;
    uint64_t bal = __ballot(conn[i] != 0);
    int lane = threadIdx.x & 63;
    size_t w0 = (i & ~(size_t)63) >> 5;
    if (lane == 0)      mp[w0]     = (uint32_t)bal;
    else if (lane == 1) mp[w0 + 1] = (uint32_t)(bal >> 32);
}

// ---------------------------------------------------------------------------
// V f32 [ROWS][512] -> Vt bf16 [16][128][2048]   (per-head transpose)
// ---------------------------------------------------------------------------
__global__ __launch_bounds__(256) void conv_vt_kernel(
    const float* __restrict__ V, __bf16* __restrict__ Vt)
{
    __shared__ float t[32][65];
    int bh = blockIdx.x, b = bh >> 2, h = bh & 3;
    int a0 = blockIdx.y * 64, d0 = blockIdx.z * 32;
#pragma unroll
    for (int i = 0; i < 2; ++i) {
        int idx = threadIdx.x + i * 256;      // 0..511
        int a_l = idx & 63;
        int dq  = (idx >> 6) * 4;             // 0..28
        float4 v = *(const float4*)(V + (size_t)(b * A_LEN + a0 + a_l) * D_DIM + h * HDIM + d0 + dq);
        t[dq + 0][a_l] = v.x; t[dq + 1][a_l] = v.y;
        t[dq + 2][a_l] = v.z; t[dq + 3][a_l] = v.w;
    }
    __syncthreads();
#pragma unroll
    for (int i = 0; i < 2; ++i) {
        int idx = threadIdx.x + i * 256;
        int d_l = idx >> 4;                   // 0..31
        int aq  = (idx & 15) * 4;             // 0..60
        bf16x4 o;
        o[0] = (__bf16)t[d_l][aq + 0]; o[1] = (__bf16)t[d_l][aq + 1];
        o[2] = (__bf16)t[d_l][aq + 2]; o[3] = (__bf16)t[d_l][aq + 3];
        *(bf16x4*)(Vt + ((size_t)bh * HDIM + d0 + d_l) * A_LEN + a0 + aq) = o;
    }
}

// ---------------------------------------------------------------------------
// bf16 MFMA GEMM: C[M=8192,N=512] = A[M,512]bf16 * W[512,512]^T bf16
// mode 0: f32 out [M][N] (+bias);  mode 1: bf16 out in head layout
//         dst[((b*4+h)*A + a)*128 + d] = C[m][n]*oscale  (m=(b,a), n=(h,d))
// grid (M/64, N/64), 256 thr = 4 waves, wave w: rows m0+16w..+15, cols n0..+63
// ---------------------------------------------------------------------------
__global__ __launch_bounds__(256, 4) void gemm_mfma(
    const __bf16* __restrict__ Am, const __bf16* __restrict__ Wm,
    const float* __restrict__ bias, void* __restrict__ Cout,
    int mode, float oscale)
{
    const int N = D_DIM, K = D_DIM;
    int w = threadIdx.x >> 6, lane = threadIdx.x & 63;
    int grp = lane >> 4, col = lane & 15;
    int m0 = blockIdx.x * 64 + w * 16;
    int n0 = blockIdx.y * 64;
    const __bf16* aptr = Am + (size_t)(m0 + col) * K + grp * 8;
    const __bf16* wptr = Wm + (size_t)(n0 + col) * K + grp * 8;
    f32x4 acc[4] = {{0,0,0,0},{0,0,0,0},{0,0,0,0},{0,0,0,0}};
#pragma unroll 2
    for (int k0 = 0; k0 < K; k0 += 32) {
        bf16x8 af  = *(const bf16x8*)(aptr + k0);
        bf16x8 b0  = *(const bf16x8*)(wptr + k0);
        bf16x8 b1  = *(const bf16x8*)(wptr + (size_t)16 * K + k0);
        bf16x8 b2  = *(const bf16x8*)(wptr + (size_t)32 * K + k0);
        bf16x8 b3  = *(const bf16x8*)(wptr + (size_t)48 * K + k0);
        acc[0] = __builtin_amdgcn_mfma_f32_16x16x32_bf16(af, b0, acc[0], 0, 0, 0);
        acc[1] = __builtin_amdgcn_mfma_f32_16x16x32_bf16(af, b1, acc[1], 0, 0, 0);
        acc[2] = __builtin_amdgcn_mfma_f32_16x16x32_bf16(af, b2, acc[2], 0, 0, 0);
        acc[3] = __builtin_amdgcn_mfma_f32_16x16x32_bf16(af, b3, acc[3], 0, 0, 0);
    }
    if (mode == 0) {
        float* C = (float*)Cout;
#pragma unroll
        for (int nt = 0; nt < 4; ++nt) {
            int n = n0 + nt * 16 + col;
            float bv = bias ? bias[n] : 0.f;
#pragma unroll
            for (int r = 0; r < 4; ++r) {
                int m = m0 + grp * 4 + r;
                C[(size_t)m * N + n] = acc[nt][r] + bv;
            }
        }
    } else {
        __bf16* Cb = (__bf16*)Cout;
#pragma unroll
        for (int nt = 0; nt < 4; ++nt) {
            int n = n0 + nt * 16 + col;
            int h = n >> 7, d = n & 127;
#pragma unroll
            for (int r = 0; r < 4; ++r) {
                int m = m0 + grp * 4 + r;
                int b = m >> 11, a = m & (A_LEN - 1);
                Cb[((size_t)(b * NHEADS + h) * A_LEN + a) * HDIM + d] =
                    (__bf16)(acc[nt][r] * oscale);
            }
        }
    }
}

// ---------------------------------------------------------------------------
// Flash-style MFMA attention.
// Qh,Kh: bf16 [16][2048][128] (softmax scale folded into Qh)
// Vt:    bf16 [16][128][2048]
// MP:    uint32 [4][2048][64] mask bits
// O:     f32 [8192][512] (head slice write)
// grid (A/64, 16), 256 thr = 4 waves, wave w owns 16 q-rows, no inter-wave sync.
// ---------------------------------------------------------------------------
__global__ __launch_bounds__(256, 2) void attn_mfma(
    const __bf16* __restrict__ Qh, const __bf16* __restrict__ Kh,
    const __bf16* __restrict__ Vt, const uint32_t* __restrict__ MP,
    float* __restrict__ O)
{
    int bh = blockIdx.y, b = bh >> 2, h = bh & 3;
    int w = threadIdx.x >> 6, lane = threadIdx.x & 63;
    int qbase = blockIdx.x * 64 + w * 16;
    int grp = lane >> 4, col = lane & 15;

    __shared__ __bf16 Pl[4][16][40];   // per-wave P tile, stride 40 (80B rows)

    // Q fragments (A operand), row = qbase+col, k-chunk c
    const __bf16* qptr = Qh + ((size_t)bh * A_LEN + qbase + col) * HDIM + grp * 8;
    bf16x8 qf[4];
#pragma unroll
    for (int c = 0; c < 4; ++c) qf[c] = *(const bf16x8*)(qptr + c * 32);

    const __bf16* kbase = Kh + (size_t)bh * A_LEN * HDIM + (size_t)col * HDIM + grp * 8;
    const __bf16* vbase = Vt + ((size_t)bh * HDIM + col) * A_LEN + grp * 8;
    const uint32_t* mpbase = MP + ((size_t)b * A_LEN + qbase + grp * 4) * (A_LEN / 32);

    float m_run[4] = {-1e30f, -1e30f, -1e30f, -1e30f};
    float l_run[4] = {0.f, 0.f, 0.f, 0.f};
    f32x4 oacc[8];
#pragma unroll
    for (int dt = 0; dt < 8; ++dt) oacc[dt] = (f32x4){0,0,0,0};

    // prefetch K fragments (B operand) for tile 0: rows t*16+col
    bf16x8 kf[8];
#pragma unroll
    for (int t = 0; t < 2; ++t)
#pragma unroll
        for (int c = 0; c < 4; ++c)
            kf[t * 4 + c] = *(const bf16x8*)(kbase + (size_t)(t * 16) * HDIM + c * 32);

#pragma unroll 1
    for (int k0 = 0; k0 < A_LEN; k0 += 32) {
        // V fragments for this tile
        bf16x8 vf[8];
#pragma unroll
        for (int dt = 0; dt < 8; ++dt)
            vf[dt] = *(const bf16x8*)(vbase + (size_t)(dt * 16) * A_LEN + k0);
        // mask words (one per owned row)
        uint32_t mw[4];
#pragma unroll
        for (int r = 0; r < 4; ++r) mw[r] = mpbase[(size_t)r * (A_LEN / 32) + (k0 >> 5)];
        // prefetch next K tile (wrap to 0 on last iter; values unused)
        int kn0 = (k0 + 32) & (A_LEN - 1);
        bf16x8 kn[8];
#pragma unroll
        for (int t = 0; t < 2; ++t)
#pragma unroll
            for (int c = 0; c < 4; ++c)
                kn[t * 4 + c] = *(const bf16x8*)(kbase + (size_t)(kn0 + t * 16) * HDIM + c * 32);

        // S = Q K^T  (two 16-col subtiles)
        f32x4 s0 = {0,0,0,0}, s1 = {0,0,0,0};
#pragma unroll
        for (int c = 0; c < 4; ++c) {
            s0 = __builtin_amdgcn_mfma_f32_16x16x32_bf16(qf[c], kf[c],     s0, 0, 0, 0);
            s1 = __builtin_amdgcn_mfma_f32_16x16x32_bf16(qf[c], kf[4 + c], s1, 0, 0, 0);
        }

        // mask + tile row-max
        float sv0[4], sv1[4], tm[4];
#pragma unroll
        for (int r = 0; r < 4; ++r) {
            sv0[r] = ((mw[r] >> col) & 1u)        ? s0[r] : -__builtin_inff();
            sv1[r] = ((mw[r] >> (16 + col)) & 1u) ? s1[r] : -__builtin_inff();
            tm[r] = fmaxf(sv0[r], sv1[r]);
        }
#pragma unroll
        for (int off = 8; off; off >>= 1)
#pragma unroll
            for (int r = 0; r < 4; ++r) tm[r] = fmaxf(tm[r], __shfl_xor(tm[r], off));

        // defer-max rescale (THR=8)
        bool need = (tm[0] > m_run[0] + 8.f) | (tm[1] > m_run[1] + 8.f) |
                    (tm[2] > m_run[2] + 8.f) | (tm[3] > m_run[3] + 8.f);
        if (need) {
#pragma unroll
            for (int r = 0; r < 4; ++r) {
                float mn = fmaxf(m_run[r], tm[r]);
                float f  = __expf(m_run[r] - mn);
                m_run[r] = mn;
                l_run[r] *= f;
#pragma unroll
                for (int dt = 0; dt < 8; ++dt) oacc[dt][r] *= f;
            }
        }

        // P = exp(S - m), row-sum, write P tile to LDS (bf16)
        float rs[4];
#pragma unroll
        for (int r = 0; r < 4; ++r) {
            float p0 = __expf(sv0[r] - m_run[r]);
            float p1 = __expf(sv1[r] - m_run[r]);
            rs[r] = p0 + p1;
            Pl[w][grp * 4 + r][col]      = (__bf16)p0;
            Pl[w][grp * 4 + r][16 + col] = (__bf16)p1;
        }
#pragma unroll
        for (int off = 8; off; off >>= 1)
#pragma unroll
            for (int r = 0; r < 4; ++r) rs[r] += __shfl_xor(rs[r], off);
#pragma unroll
        for (int r = 0; r < 4; ++r) l_run[r] += rs[r];

        // P as A-operand fragment (wave-internal LDS round trip)
        bf16x8 pa = *(const bf16x8*)&Pl[w][col][grp * 8];

        // O += P V
#pragma unroll
        for (int dt = 0; dt < 8; ++dt)
            oacc[dt] = __builtin_amdgcn_mfma_f32_16x16x32_bf16(pa, vf[dt], oacc[dt], 0, 0, 0);

#pragma unroll
        for (int i = 0; i < 8; ++i) kf[i] = kn[i];
    }

    // normalize + write head slice
    float* optr = O + ((size_t)b * A_LEN + qbase + grp * 4) * D_DIM + h * HDIM + col;
#pragma unroll
    for (int r = 0; r < 4; ++r) {
        float inv = 1.f / l_run[r];
#pragma unroll
        for (int dt = 0; dt < 8; ++dt)
            optr[(size_t)r * D_DIM + dt * 16] = oacc[dt][r] * inv;
    }
}

// ---------------------------------------------------------------------------
extern "C" void kernel_launch(void* const* d_in, const int* in_sizes, int n_in,
                              void* d_out, int out_size, void* d_ws, size_t ws_size,
                              hipStream_t stream)
{
    const float* x      = (const float*)d_in[0];
    const int*   conn   = (const int*)d_in[1];
    const float* Wq     = (const float*)d_in[2];
    const float* Wk     = (const float*)d_in[3];
    const float* Wv     = (const float*)d_in[4];
    const float* norm_w = (const float*)d_in[5];
    const float* norm_b = (const float*)d_in[6];
    const float* ln1_w  = (const float*)d_in[7];
    const float* ln1_b  = (const float*)d_in[8];
    const float* fc1_w  = (const float*)d_in[9];
    const float* fc1_b  = (const float*)d_in[10];
    const float* ln2_w  = (const float*)d_in[11];
    const float* ln2_b  = (const float*)d_in[12];
    const float* fc2_w  = (const float*)d_in[13];
    const float* fc2_b  = (const float*)d_in[14];
    float* out = (float*)d_out;

    char* wsb = (char*)d_ws;
    const size_t WELEM = (size_t)D_DIM * D_DIM;          // 262144
    __bf16*   wqb = (__bf16*)(wsb + 0);                  // 5 x 512KB
    __bf16*   wkb = wqb + WELEM;
    __bf16*   wvb = wkb + WELEM;
    __bf16*   w1b = wvb + WELEM;
    __bf16*   w2b = w1b + WELEM;
    __bf16*   xb  = (__bf16*)(wsb + ((size_t)3  << 20)); // bf16 act [8192][512], 8MB
    __bf16*   Qh  = (__bf16*)(wsb + ((size_t)11 << 20)); // 8MB
    __bf16*   Kh  = (__bf16*)(wsb + ((size_t)19 << 20)); // 8MB
    float*    Vb  = (float*)(wsb + ((size_t)27 << 20));  // 16MB
    __bf16*   Vt  = (__bf16*)(wsb + ((size_t)43 << 20)); // 8MB
    uint32_t* mp  = (uint32_t*)(wsb + ((size_t)51 << 20)); // 2MB
    float*    Ob  = (float*)(wsb + ((size_t)27 << 20));  // alias Vb (dead after conv_vt)
    float*    h1  = (float*)(wsb + ((size_t)11 << 20));  // alias Qh+Kh (dead after attn)
    float*    h2  = (float*)(wsb + ((size_t)27 << 20));  // alias Ob (dead after ln1)

    dim3 blk(256);
    dim3 lnGrid(ROWS / 4);
    dim3 gemmGrid(ROWS / 64, D_DIM / 64);
    dim3 attnGrid(A_LEN / 64, B_SZ * NHEADS);
    dim3 vtGrid(B_SZ * NHEADS, A_LEN / 64, HDIM / 32);
    dim3 wGrid(WELEM / 8 / 256);
    dim3 mpGrid((size_t)B_SZ * A_LEN * A_LEN / 256);

    const float QSCALE = 0.08838834764831845f;  // 1/sqrt(128)

    conv_w_kernel<<<wGrid, blk, 0, stream>>>(Wq, wqb);
    conv_w_kernel<<<wGrid, blk, 0, stream>>>(Wk, wkb);
    conv_w_kernel<<<wGrid, blk, 0, stream>>>(Wv, wvb);
    conv_w_kernel<<<wGrid, blk, 0, stream>>>(fc1_w, w1b);
    conv_w_kernel<<<wGrid, blk, 0, stream>>>(fc2_w, w2b);
    mask_pack_kernel<<<mpGrid, blk, 0, stream>>>(conn, mp);

    // xb = LN(x) (bf16)
    ln_kernel<<<lnGrid, blk, 0, stream>>>(x, xb, norm_w, norm_b, 0, 1);
    // Qh/Kh bf16 head-layout (scale folded into Q); Vb f32
    gemm_mfma<<<gemmGrid, blk, 0, stream>>>(xb, wqb, nullptr, Qh, 1, QSCALE);
    gemm_mfma<<<gemmGrid, blk, 0, stream>>>(xb, wkb, nullptr, Kh, 1, 1.0f);
    gemm_mfma<<<gemmGrid, blk, 0, stream>>>(xb, wvb, nullptr, Vb, 0, 1.0f);
    conv_vt_kernel<<<vtGrid, blk, 0, stream>>>(Vb, Vt);
    // attention -> Ob (f32)
    attn_mfma<<<attnGrid, blk, 0, stream>>>(Qh, Kh, Vt, mp, Ob);
    // y1 = LN(swish(Ob)) bf16 -> xb
    ln_kernel<<<lnGrid, blk, 0, stream>>>(Ob, xb, ln1_w, ln1_b, 1, 1);
    // h1 = y1 @ fc1^T + b1 (f32)
    gemm_mfma<<<gemmGrid, blk, 0, stream>>>(xb, w1b, fc1_b, h1, 0, 1.0f);
    // y2 = LN(swish(h1)) bf16 -> xb
    ln_kernel<<<lnGrid, blk, 0, stream>>>(h1, xb, ln2_w, ln2_b, 1, 1);
    // h2 = y2 @ fc2^T + b2 (f32)
    gemm_mfma<<<gemmGrid, blk, 0, stream>>>(xb, w2b, fc2_b, h2, 0, 1.0f);
    // out = LN(h2) (f32)
    ln_kernel<<<lnGrid, blk, 0, stream>>>(h2, out, norm_w, norm_b, 0, 0);
}